// Round 1
// baseline (281.162 us; speedup 1.0000x reference)
//
#include <hip/hip_runtime.h>
#include <hip/hip_bf16.h>

// GCN layer: out[b,n,o] = dis[b,n] * sum_m adj[b,n,m] * dis[b,m] * (x[b,m,:]@W[o,:] + bias[o])
// dis[b,n] = (rowsum(adj[b,n,:]) - adj[b,n,n])^-1/2
//
// Plan:
//  K1: dis[b,n] (fp32, one block per row)
//  K2: hT[o, b*2048+m] = dis * (x@W^T + b), bf16, stored o-major so K3's B-operand
//      is k-contiguous (both K2 operands are naturally k-contiguous off row-major W,x)
//  K3: out = dis[n] * (adj_bf16 @ hT) per batch; batch = blockIdx&7 for XCD-L2 affinity.

#define BATCH 8
#define NN    2048
#define DIN   256
#define DOUT  256
#define RTOT  (BATCH * NN)   // 16384

typedef short  bf16x8  __attribute__((ext_vector_type(8)));
typedef short  short4v __attribute__((ext_vector_type(4)));
typedef float  f32x4   __attribute__((ext_vector_type(4)));

__device__ __forceinline__ short f2bf(float f) {
    union { float f; unsigned u; } v; v.f = f;
    unsigned r = v.u + 0x7fffu + ((v.u >> 16) & 1u);   // RNE truncate to bf16
    return (short)(r >> 16);
}

// ---------------- K1: degrees -> dis ----------------
__global__ __launch_bounds__(256) void k_degree(const float* __restrict__ adj,
                                                float* __restrict__ dis) {
    int row = blockIdx.x;                 // 0..16383
    int b = row >> 11, n = row & (NN - 1);
    const float4* rp4 = (const float4*)(adj + ((size_t)b * NN + n) * NN);
    float s = 0.f;
#pragma unroll
    for (int i = 0; i < 2; i++) {
        float4 v = rp4[threadIdx.x + i * 256];
        s += (v.x + v.y) + (v.z + v.w);
    }
#pragma unroll
    for (int off = 32; off; off >>= 1) s += __shfl_down(s, off);
    __shared__ float red[4];
    if ((threadIdx.x & 63) == 0) red[threadIdx.x >> 6] = s;
    __syncthreads();
    if (threadIdx.x == 0) {
        float tot  = (red[0] + red[1]) + (red[2] + red[3]);
        float diag = ((const float*)rp4)[n];
        dis[row]   = rsqrtf(tot - diag);
    }
}

// ---------------- K2: projection, transposed + dis-folded ----------------
// hT[o, r] = dis[r] * (sum_d W[o,d] * x[r,d] + bias[o]);  M'=256(o), N'=16384(r), K=256
__global__ __launch_bounds__(256) void k_proj(const float* __restrict__ x,
                                              const float* __restrict__ W,
                                              const float* __restrict__ bias,
                                              const float* __restrict__ dis,
                                              unsigned short* __restrict__ hT) {
    const int mt  = blockIdx.y;           // 0..1   (o-tile of 128)
    const int nt  = blockIdx.x;           // 0..127 (r-tile of 128)
    const int tid = threadIdx.x;
    const int w = tid >> 6, lane = tid & 63;
    const int wr = w >> 1, wc = w & 1;
    const int l16 = lane & 15, quad = lane >> 4;

    __shared__ short As[128][32];   // W rows (o), k-contig
    __shared__ short Bs[128][32];   // x rows (r), k-contig

    f32x4 acc[4][4];
#pragma unroll
    for (int i = 0; i < 4; i++)
#pragma unroll
        for (int j = 0; j < 4; j++) acc[i][j] = (f32x4){0.f, 0.f, 0.f, 0.f};

    const float4* Wf4 = (const float4*)(W + (size_t)mt * 128 * DIN);
    const float4* Xf4 = (const float4*)(x + (size_t)nt * 128 * DIN);

    for (int kk = 0; kk < DIN / 32; kk++) {
        const int k0 = kk * 32;
        __syncthreads();
#pragma unroll
        for (int it = 0; it < 4; it++) {
            int idx = tid + it * 256;           // 0..1023: 128 rows x 8 float4
            int r = idx >> 3, c = idx & 7;
            float4 va = Wf4[(size_t)r * (DIN / 4) + (k0 >> 2) + c];
            float4 vb = Xf4[(size_t)r * (DIN / 4) + (k0 >> 2) + c];
            short4v sa = { f2bf(va.x), f2bf(va.y), f2bf(va.z), f2bf(va.w) };
            short4v sb = { f2bf(vb.x), f2bf(vb.y), f2bf(vb.z), f2bf(vb.w) };
            *(short4v*)&As[r][c * 4] = sa;
            *(short4v*)&Bs[r][c * 4] = sb;
        }
        __syncthreads();
        bf16x8 af[4], bfv[4];
#pragma unroll
        for (int i = 0; i < 4; i++) af[i]  = *(bf16x8*)&As[wr * 64 + i * 16 + l16][quad * 8];
#pragma unroll
        for (int j = 0; j < 4; j++) bfv[j] = *(bf16x8*)&Bs[wc * 64 + j * 16 + l16][quad * 8];
#pragma unroll
        for (int i = 0; i < 4; i++)
#pragma unroll
            for (int j = 0; j < 4; j++)
                acc[i][j] = __builtin_amdgcn_mfma_f32_16x16x32_bf16(af[i], bfv[j], acc[i][j], 0, 0, 0);
    }

#pragma unroll
    for (int i = 0; i < 4; i++) {
        const int orow_base = mt * 128 + wr * 64 + i * 16 + quad * 4;
#pragma unroll
        for (int r = 0; r < 4; r++) {
            const int orow = orow_base + r;
            const float bb = bias[orow];
#pragma unroll
            for (int j = 0; j < 4; j++) {
                const int col = nt * 128 + wc * 64 + j * 16 + l16;
                float v = (acc[i][j][r] + bb) * dis[col];
                hT[(size_t)orow * RTOT + col] = (unsigned short)f2bf(v);
            }
        }
    }
}

// ---------------- K3: out = dis[n] * (adj @ hT) ----------------
// Per batch: M=2048(n), K=2048(m), N=256(o). Block tile 64x256, 4 waves of 64x64.
__global__ __launch_bounds__(256) void k_main(const float* __restrict__ adj,
                                              const unsigned short* __restrict__ hT,
                                              const float* __restrict__ dis,
                                              float* __restrict__ out) {
    const int b     = blockIdx.x & 7;     // XCD-affine batch
    const int mtile = blockIdx.x >> 3;    // 0..31
    const int n0    = mtile * 64;
    const int tid = threadIdx.x;
    const int w = tid >> 6, lane = tid & 63;
    const int l16 = lane & 15, quad = lane >> 4;

    __shared__ short As[64][32];    // adj rows(n) x k(m), bf16
    __shared__ short Bs[256][32];   // hT rows(o) x k(m), bf16

    f32x4 acc[4][4];
#pragma unroll
    for (int i = 0; i < 4; i++)
#pragma unroll
        for (int j = 0; j < 4; j++) acc[i][j] = (f32x4){0.f, 0.f, 0.f, 0.f};

    const float4* adj4 = (const float4*)(adj + ((size_t)b * NN + n0) * NN);
    const unsigned short* hTb = hT + (size_t)b * NN;   // column offset within rows of stride RTOT

    for (int kk = 0; kk < NN / 32; kk++) {
        const int k0 = kk * 32;
        __syncthreads();
        // A: 64 rows x 8 float4 = 512 -> 2 per thread
#pragma unroll
        for (int it = 0; it < 2; it++) {
            int idx = tid + it * 256;
            int r = idx >> 3, c = idx & 7;
            float4 v = adj4[(size_t)r * (NN / 4) + (k0 >> 2) + c];
            short4v sv = { f2bf(v.x), f2bf(v.y), f2bf(v.z), f2bf(v.w) };
            *(short4v*)&As[r][c * 4] = sv;
        }
        // B: 256 rows x 4 chunks of 8 bf16 = 1024 -> 4 per thread
#pragma unroll
        for (int it = 0; it < 4; it++) {
            int idx = tid + it * 256;
            int o = idx >> 2, c = idx & 3;
            bf16x8 hv = *(const bf16x8*)(hTb + (size_t)o * RTOT + k0 + c * 8);
            *(bf16x8*)&Bs[o][c * 8] = hv;
        }
        __syncthreads();
        bf16x8 af[4], bfv[4];
#pragma unroll
        for (int i = 0; i < 4; i++) af[i]  = *(bf16x8*)&As[i * 16 + l16][quad * 8];
#pragma unroll
        for (int j = 0; j < 4; j++) bfv[j] = *(bf16x8*)&Bs[w * 64 + j * 16 + l16][quad * 8];
#pragma unroll
        for (int i = 0; i < 4; i++)
#pragma unroll
            for (int j = 0; j < 4; j++)
                acc[i][j] = __builtin_amdgcn_mfma_f32_16x16x32_bf16(af[i], bfv[j], acc[i][j], 0, 0, 0);
    }

    const float* disb = dis + (size_t)b * NN;
#pragma unroll
    for (int i = 0; i < 4; i++) {
#pragma unroll
        for (int r = 0; r < 4; r++) {
            const int nrow = n0 + i * 16 + quad * 4 + r;
            const float dn = disb[nrow];
#pragma unroll
            for (int j = 0; j < 4; j++) {
                const int ocol = w * 64 + j * 16 + l16;
                out[((size_t)b * NN + nrow) * DOUT + ocol] = dn * acc[i][j][r];
            }
        }
    }
}

extern "C" void kernel_launch(void* const* d_in, const int* in_sizes, int n_in,
                              void* d_out, int out_size, void* d_ws, size_t ws_size,
                              hipStream_t stream) {
    const float* x    = (const float*)d_in[0];
    const float* adj  = (const float*)d_in[1];
    const float* W    = (const float*)d_in[2];
    const float* bias = (const float*)d_in[3];
    float* out = (float*)d_out;

    float* dis = (float*)d_ws;                                     // 64 KB
    unsigned short* hT = (unsigned short*)((char*)d_ws + 65536);   // 8 MB bf16 [256][16384]

    k_degree<<<RTOT, 256, 0, stream>>>(adj, dis);
    k_proj<<<dim3(128, 2), 256, 0, stream>>>(x, W, bias, dis, hT);
    k_main<<<256, 256, 0, stream>>>(adj, hT, dis, out);
}